// Round 5
// baseline (149.596 us; speedup 1.0000x reference)
//
#include <hip/hip_runtime.h>

// AttnCutLoss: loss = -(1/B) * sum_b [ (sum_s log(output[b,s])) / (sum_s exp(r_bs/TAU)) ]
// r_bs = 2*tp_bs / (k + total_b)   (F1, algebraically simplified; exact for the
// reference's tp=0 / total=0 where() branches).  B = S = 4096, TAU = 0.95, fp32.
//
// Single kernel: R2's 1-row-per-256-thread-block structure + fused final
// reduction via last-block pattern (device-scope fence + atomic counter in d_ws).

#define BDIM 256
#define VPT 16              // values per thread; BDIM*VPT == SROW
#define SROW 4096
#define NROWS 4096

__global__ __launch_bounds__(BDIM) void attncut_fused_kernel(
    const float* __restrict__ output,   // [B,S,1]
    const float* __restrict__ labels,   // [B,S]
    float* __restrict__ row_out,        // [B] scratch: L_b / norm_b
    unsigned int* __restrict__ done_ctr,// 1 uint scratch, zeroed per call
    float* __restrict__ d_out)          // [1] final loss
{
    const int b    = blockIdx.x;
    const int tid  = threadIdx.x;       // 0..255
    const int lane = tid & 63;
    const int wave = tid >> 6;          // 0..3
    const int base = tid * VPT;

    const float* lab = labels + (size_t)b * SROW + base;
    const float* out = output + (size_t)b * SROW + base;

    // Issue ALL loads up front so both arrays' latency overlaps the scan.
    float4 Lv[4], Ov[4];
    #pragma unroll
    for (int i = 0; i < 4; ++i) Lv[i] = reinterpret_cast<const float4*>(lab)[i];
    #pragma unroll
    for (int i = 0; i < 4; ++i) Ov[i] = reinterpret_cast<const float4*>(out)[i];

    float v[VPT], o[VPT];
    #pragma unroll
    for (int i = 0; i < 4; ++i) {
        v[4*i+0] = Lv[i].x; v[4*i+1] = Lv[i].y; v[4*i+2] = Lv[i].z; v[4*i+3] = Lv[i].w;
        o[4*i+0] = Ov[i].x; o[4*i+1] = Ov[i].y; o[4*i+2] = Ov[i].z; o[4*i+3] = Ov[i].w;
    }

    // Thread-local inclusive prefix of labels (exact: labels are 0.0/1.0).
    float pre[VPT];
    float acc = 0.f;
    #pragma unroll
    for (int i = 0; i < VPT; ++i) { acc += v[i]; pre[i] = acc; }
    const float cnt = acc;

    // Log-sum: trans-pipe work overlapping other waves' scan/barriers.
    float lsum = 0.f;
    #pragma unroll
    for (int i = 0; i < VPT; ++i) lsum += __logf(o[i]);

    // Wave-level inclusive scan of per-thread counts.
    float sc = cnt;
    #pragma unroll
    for (int d = 1; d < 64; d <<= 1) {
        float n = __shfl_up(sc, d, 64);
        if (lane >= d) sc += n;
    }

    __shared__ float wtot[4], wpre[4];
    __shared__ float s_total;
    if (lane == 63) wtot[wave] = sc;
    __syncthreads();
    if (tid == 0) {
        float a = 0.f;
        #pragma unroll
        for (int w = 0; w < 4; ++w) { wpre[w] = a; a += wtot[w]; }
        s_total = a;
    }
    __syncthreads();
    const float total = s_total;
    const float excl  = wpre[wave] + (sc - cnt);   // labels strictly before this chunk

    // qsum = sum exp(2*tp / (TAU*(k+total))), fast rcp for the divide.
    const float c = 2.0f / 0.95f;
    float qsum = 0.f;
    #pragma unroll
    for (int i = 0; i < VPT; ++i) {
        float tp = excl + pre[i];
        float kf = (float)(base + i + 1) + total;
        qsum += __expf(c * tp * __builtin_amdgcn_rcpf(kf));
    }

    // Block reduction of (qsum, lsum).
    #pragma unroll
    for (int d = 32; d > 0; d >>= 1) {
        qsum += __shfl_down(qsum, d, 64);
        lsum += __shfl_down(lsum, d, 64);
    }
    __shared__ float sq[4], sl[4];
    __shared__ bool s_last;
    if (lane == 0) { sq[wave] = qsum; sl[wave] = lsum; }
    __syncthreads();
    if (tid == 0) {
        float Q = 0.f, L = 0.f;
        #pragma unroll
        for (int w = 0; w < 4; ++w) { Q += sq[w]; L += sl[w]; }
        row_out[b] = L / Q;
        __threadfence();                            // release: row result visible device-wide
        unsigned int t = atomicAdd(done_ctr, 1u);   // device-scope
        s_last = (t == NROWS - 1);
    }
    __syncthreads();

    // Last block standing reduces all 4096 row values (fixed order -> deterministic).
    if (s_last) {
        __threadfence();                            // acquire: drop stale L1/L2 lines
        float s = 0.f;
        for (int i = tid; i < NROWS; i += BDIM) s += row_out[i];
        #pragma unroll
        for (int d = 32; d > 0; d >>= 1) s += __shfl_down(s, d, 64);
        if (lane == 0) sq[wave] = s;                // reuse sq[]
        __syncthreads();
        if (tid == 0) {
            float t = 0.f;
            #pragma unroll
            for (int w = 0; w < 4; ++w) t += sq[w];
            d_out[0] = -t / (float)NROWS;
        }
    }
}

extern "C" void kernel_launch(void* const* d_in, const int* in_sizes, int n_in,
                              void* d_out, int out_size, void* d_ws, size_t ws_size,
                              hipStream_t stream) {
    const float* output = (const float*)d_in[0];   // [B,S,1] fp32
    const float* labels = (const float*)d_in[1];   // [B,S]   fp32
    float* out  = (float*)d_out;
    float* rows = (float*)d_ws;                    // NROWS floats
    unsigned int* ctr = (unsigned int*)((char*)d_ws + NROWS * sizeof(float));

    hipMemsetAsync(ctr, 0, sizeof(unsigned int), stream);   // graph-capturable
    attncut_fused_kernel<<<NROWS, BDIM, 0, stream>>>(output, labels, rows, ctr, out);
}

// Round 6
// 69.005 us; speedup vs baseline: 2.1679x; 2.1679x over previous
//
#include <hip/hip_runtime.h>

// AttnCutLoss: loss = -(1/B) * sum_b [ (sum_s log(output[b,s])) / (sum_s exp(r_bs/TAU)) ]
// r_bs = 2*tp_bs / (k + total_b)   (F1, algebraically simplified; exact for the
// reference's tp=0 / total=0 where() branches).  B = S = 4096, TAU = 0.95, fp32.
//
// Lane-contiguous loads: thread t reads float4 index (t + k*256) -> every wave
// memory instruction covers 1 KB contiguous (16 cache lines), not 4 KB sparse.
// Hierarchical label scan: per-chunk wave scans + 16-value LDS scan.
// Final reduction fused via one float atomicAdd per block (no fences).

#define BDIM 256
#define NCH 4               // float4 chunks per thread; BDIM*NCH*4 == SROW
#define SROW 4096
#define NROWS 4096

__global__ __launch_bounds__(BDIM) void attncut_fused_kernel(
    const float* __restrict__ output,   // [B,S,1]
    const float* __restrict__ labels,   // [B,S]
    float* __restrict__ d_out)          // [1], zeroed per call
{
    const int b    = blockIdx.x;
    const int tid  = threadIdx.x;       // 0..255
    const int lane = tid & 63;
    const int wave = tid >> 6;          // 0..3

    const float4* lab4 = reinterpret_cast<const float4*>(labels) + (size_t)b * (SROW / 4) + tid;
    const float4* out4 = reinterpret_cast<const float4*>(output) + (size_t)b * (SROW / 4) + tid;

    // Issue all loads up front; each instruction is 1 KB contiguous per wave.
    float4 Lv[NCH], Ov[NCH];
    #pragma unroll
    for (int k = 0; k < NCH; ++k) Lv[k] = lab4[k * BDIM];
    #pragma unroll
    for (int k = 0; k < NCH; ++k) Ov[k] = out4[k * BDIM];

    // Per-chunk local inclusive prefixes (labels are exactly 0.0/1.0 -> exact).
    float p[NCH][4], s[NCH];
    #pragma unroll
    for (int k = 0; k < NCH; ++k) {
        p[k][0] = Lv[k].x;
        p[k][1] = p[k][0] + Lv[k].y;
        p[k][2] = p[k][1] + Lv[k].z;
        p[k][3] = p[k][2] + Lv[k].w;
        s[k]    = p[k][3];
    }

    // 4 independent wave-level inclusive scans (good ILP, pure VALU).
    float sc[NCH];
    #pragma unroll
    for (int k = 0; k < NCH; ++k) sc[k] = s[k];
    #pragma unroll
    for (int d = 1; d < 64; d <<= 1) {
        #pragma unroll
        for (int k = 0; k < NCH; ++k) {
            float n = __shfl_up(sc[k], d, 64);
            if (lane >= d) sc[k] += n;
        }
    }

    // lsum here: O-loads have had the whole scan to arrive.
    float lsum = 0.f;
    #pragma unroll
    for (int k = 0; k < NCH; ++k)
        lsum += __logf(Ov[k].x) + __logf(Ov[k].y) + __logf(Ov[k].z) + __logf(Ov[k].w);

    // Cross-wave / cross-chunk exclusive prefixes via 16-value LDS scan.
    __shared__ float wtot[NCH * 4], wpre[NCH * 4];
    __shared__ float s_total;
    if (lane == 63) {
        #pragma unroll
        for (int k = 0; k < NCH; ++k) wtot[k * 4 + wave] = sc[k];
    }
    __syncthreads();
    if (tid == 0) {
        float a = 0.f;
        #pragma unroll
        for (int i = 0; i < NCH * 4; ++i) { wpre[i] = a; a += wtot[i]; }
        s_total = a;
    }
    __syncthreads();
    const float total = s_total;

    // qsum = sum exp(2*tp / (TAU*(rank+total))), fast rcp for the divide.
    const float c = 2.0f / 0.95f;
    float qsum = 0.f;
    #pragma unroll
    for (int k = 0; k < NCH; ++k) {
        const float excl = wpre[k * 4 + wave] + (sc[k] - s[k]);
        const float rbase = (float)(4 * (k * BDIM + tid) + 1) + total;
        #pragma unroll
        for (int j = 0; j < 4; ++j) {
            float tp = excl + p[k][j];
            qsum += __expf(c * tp * __builtin_amdgcn_rcpf(rbase + (float)j));
        }
    }

    // Block reduction of (qsum, lsum).
    #pragma unroll
    for (int d = 32; d > 0; d >>= 1) {
        qsum += __shfl_down(qsum, d, 64);
        lsum += __shfl_down(lsum, d, 64);
    }
    __shared__ float sq[4], sl[4];
    if (lane == 0) { sq[wave] = qsum; sl[wave] = lsum; }
    __syncthreads();
    if (tid == 0) {
        float Q = 0.f, L = 0.f;
        #pragma unroll
        for (int w = 0; w < 4; ++w) { Q += sq[w]; L += sl[w]; }
        // One coherent atomic per block; pre-scaled so no final kernel needed.
        atomicAdd(d_out, -(L / Q) * (1.0f / (float)NROWS));
    }
}

extern "C" void kernel_launch(void* const* d_in, const int* in_sizes, int n_in,
                              void* d_out, int out_size, void* d_ws, size_t ws_size,
                              hipStream_t stream) {
    const float* output = (const float*)d_in[0];   // [B,S,1] fp32
    const float* labels = (const float*)d_in[1];   // [B,S]   fp32
    float* out = (float*)d_out;

    hipMemsetAsync(out, 0, sizeof(float), stream); // graph-capturable async op
    attncut_fused_kernel<<<NROWS, BDIM, 0, stream>>>(output, labels, out);
}

// Round 7
// 28.670 us; speedup vs baseline: 5.2178x; 2.4068x over previous
//
#include <hip/hip_runtime.h>

// AttnCutLoss: loss = -(1/B) * sum_b [ (sum_s log(output[b,s])) / (sum_s exp(r_bs/TAU)) ]
// r_bs = 2*tp_bs / (k + total_b)   (F1, algebraically simplified; exact for the
// reference's tp=0 / total=0 where() branches).  B = S = 4096, TAU = 0.95, fp32.
//
// Lane-contiguous loads (each wave instr = 1 KB contiguous), hierarchical label
// scan (4 wave scans + 16-value LDS scan). Two-kernel tree reduction — NO
// single-address atomics (R5/R6 showed 4096 same-address atomics cost ~40+ us).

#define BDIM 256
#define NCH 4               // float4 chunks per thread; BDIM*NCH*4 == SROW
#define SROW 4096
#define NROWS 4096

__global__ __launch_bounds__(BDIM) void attncut_row_kernel(
    const float* __restrict__ output,   // [B,S,1]
    const float* __restrict__ labels,   // [B,S]
    float* __restrict__ row_out)        // [B] : L_b / norm_b
{
    const int b    = blockIdx.x;
    const int tid  = threadIdx.x;       // 0..255
    const int lane = tid & 63;
    const int wave = tid >> 6;          // 0..3

    const float4* lab4 = reinterpret_cast<const float4*>(labels) + (size_t)b * (SROW / 4) + tid;
    const float4* out4 = reinterpret_cast<const float4*>(output) + (size_t)b * (SROW / 4) + tid;

    // Issue all loads up front; each instruction is 1 KB contiguous per wave.
    float4 Lv[NCH], Ov[NCH];
    #pragma unroll
    for (int k = 0; k < NCH; ++k) Lv[k] = lab4[k * BDIM];
    #pragma unroll
    for (int k = 0; k < NCH; ++k) Ov[k] = out4[k * BDIM];

    // Per-chunk local inclusive prefixes (labels are exactly 0.0/1.0 -> exact).
    float p[NCH][4], s[NCH];
    #pragma unroll
    for (int k = 0; k < NCH; ++k) {
        p[k][0] = Lv[k].x;
        p[k][1] = p[k][0] + Lv[k].y;
        p[k][2] = p[k][1] + Lv[k].z;
        p[k][3] = p[k][2] + Lv[k].w;
        s[k]    = p[k][3];
    }

    // 4 independent wave-level inclusive scans (good ILP, pure VALU).
    float sc[NCH];
    #pragma unroll
    for (int k = 0; k < NCH; ++k) sc[k] = s[k];
    #pragma unroll
    for (int d = 1; d < 64; d <<= 1) {
        #pragma unroll
        for (int k = 0; k < NCH; ++k) {
            float n = __shfl_up(sc[k], d, 64);
            if (lane >= d) sc[k] += n;
        }
    }

    // lsum here: O-loads have had the whole scan to arrive.
    float lsum = 0.f;
    #pragma unroll
    for (int k = 0; k < NCH; ++k)
        lsum += __logf(Ov[k].x) + __logf(Ov[k].y) + __logf(Ov[k].z) + __logf(Ov[k].w);

    // Cross-wave / cross-chunk exclusive prefixes via 16-value LDS scan.
    // Row order is chunk-major: position = (k*BDIM + tid)*4 + j, so the scan
    // order over (k, wave) must be k-major: index = k*4 + wave.
    __shared__ float wtot[NCH * 4], wpre[NCH * 4];
    __shared__ float s_total;
    if (lane == 63) {
        #pragma unroll
        for (int k = 0; k < NCH; ++k) wtot[k * 4 + wave] = sc[k];
    }
    __syncthreads();
    if (tid == 0) {
        float a = 0.f;
        #pragma unroll
        for (int i = 0; i < NCH * 4; ++i) { wpre[i] = a; a += wtot[i]; }
        s_total = a;
    }
    __syncthreads();
    const float total = s_total;

    // qsum = sum exp(2*tp / (TAU*(rank+total))), fast rcp for the divide.
    const float c = 2.0f / 0.95f;
    float qsum = 0.f;
    #pragma unroll
    for (int k = 0; k < NCH; ++k) {
        const float excl = wpre[k * 4 + wave] + (sc[k] - s[k]);
        const float rbase = (float)(4 * (k * BDIM + tid) + 1) + total;
        #pragma unroll
        for (int j = 0; j < 4; ++j) {
            float tp = excl + p[k][j];
            qsum += __expf(c * tp * __builtin_amdgcn_rcpf(rbase + (float)j));
        }
    }

    // Block reduction of (qsum, lsum).
    #pragma unroll
    for (int d = 32; d > 0; d >>= 1) {
        qsum += __shfl_down(qsum, d, 64);
        lsum += __shfl_down(lsum, d, 64);
    }
    __shared__ float sq[4], sl[4];
    if (lane == 0) { sq[wave] = qsum; sl[wave] = lsum; }
    __syncthreads();
    if (tid == 0) {
        float Q = 0.f, L = 0.f;
        #pragma unroll
        for (int w = 0; w < 4; ++w) { Q += sq[w]; L += sl[w]; }
        row_out[b] = L / Q;
    }
}

__global__ __launch_bounds__(256) void attncut_final_kernel(
    const float* __restrict__ row_out, float* __restrict__ d_out)
{
    const int tid = threadIdx.x;            // 0..255
    const int lane = tid & 63, wave = tid >> 6;
    // 4096 floats = 1024 float4; thread t reads float4 t and t+256, etc.
    const float4* r4 = reinterpret_cast<const float4*>(row_out);
    float s = 0.f;
    #pragma unroll
    for (int k = 0; k < 4; ++k) {
        float4 v = r4[tid + k * 256];
        s += v.x + v.y + v.z + v.w;
    }
    #pragma unroll
    for (int d = 32; d > 0; d >>= 1) s += __shfl_down(s, d, 64);
    __shared__ float sm[4];
    if (lane == 0) sm[wave] = s;
    __syncthreads();
    if (tid == 0) {
        float t = sm[0] + sm[1] + sm[2] + sm[3];
        d_out[0] = -t / (float)NROWS;
    }
}

extern "C" void kernel_launch(void* const* d_in, const int* in_sizes, int n_in,
                              void* d_out, int out_size, void* d_ws, size_t ws_size,
                              hipStream_t stream) {
    const float* output = (const float*)d_in[0];   // [B,S,1] fp32
    const float* labels = (const float*)d_in[1];   // [B,S]   fp32
    float* out  = (float*)d_out;
    float* rows = (float*)d_ws;                    // NROWS floats of scratch

    attncut_row_kernel<<<NROWS, BDIM, 0, stream>>>(output, labels, rows);
    attncut_final_kernel<<<1, 256, 0, stream>>>(rows, out);
}

// Round 9
// 26.405 us; speedup vs baseline: 5.6655x; 1.0858x over previous
//
#include <hip/hip_runtime.h>

// AttnCutLoss: loss = -(1/B) * sum_b [ (sum_s log(output[b,s])) / (sum_s exp(r_bs/TAU)) ]
// r_bs = 2*tp_bs / (k + total_b)   (F1, algebraically simplified; exact for the
// reference's tp=0 / total=0 where() branches).  B = S = 4096, TAU = 0.95, fp32.
//
// R7 structure + single change: nontemporal (nt, evict-first) loads for both
// streamed input arrays via clang ext-vector float4 (HIP_vector_type is not
// accepted by __builtin_nontemporal_load).

#define BDIM 256
#define NCH 4               // float4 chunks per thread; BDIM*NCH*4 == SROW
#define SROW 4096
#define NROWS 4096

typedef float vf4 __attribute__((ext_vector_type(4)));

__global__ __launch_bounds__(BDIM) void attncut_row_kernel(
    const float* __restrict__ output,   // [B,S,1]
    const float* __restrict__ labels,   // [B,S]
    float* __restrict__ row_out)        // [B] : L_b / norm_b
{
    const int b    = blockIdx.x;
    const int tid  = threadIdx.x;       // 0..255
    const int lane = tid & 63;
    const int wave = tid >> 6;          // 0..3

    const vf4* lab4 = reinterpret_cast<const vf4*>(labels) + (size_t)b * (SROW / 4) + tid;
    const vf4* out4 = reinterpret_cast<const vf4*>(output) + (size_t)b * (SROW / 4) + tid;

    // Issue all loads up front; nt flag = no L2 allocate / evict-first.
    vf4 Lv[NCH], Ov[NCH];
    #pragma unroll
    for (int k = 0; k < NCH; ++k) Lv[k] = __builtin_nontemporal_load(&lab4[k * BDIM]);
    #pragma unroll
    for (int k = 0; k < NCH; ++k) Ov[k] = __builtin_nontemporal_load(&out4[k * BDIM]);

    // Per-chunk local inclusive prefixes (labels are exactly 0.0/1.0 -> exact).
    float p[NCH][4], s[NCH];
    #pragma unroll
    for (int k = 0; k < NCH; ++k) {
        p[k][0] = Lv[k].x;
        p[k][1] = p[k][0] + Lv[k].y;
        p[k][2] = p[k][1] + Lv[k].z;
        p[k][3] = p[k][2] + Lv[k].w;
        s[k]    = p[k][3];
    }

    // 4 independent wave-level inclusive scans (good ILP, pure VALU).
    float sc[NCH];
    #pragma unroll
    for (int k = 0; k < NCH; ++k) sc[k] = s[k];
    #pragma unroll
    for (int d = 1; d < 64; d <<= 1) {
        #pragma unroll
        for (int k = 0; k < NCH; ++k) {
            float n = __shfl_up(sc[k], d, 64);
            if (lane >= d) sc[k] += n;
        }
    }

    // lsum here: O-loads have had the whole scan to arrive.
    float lsum = 0.f;
    #pragma unroll
    for (int k = 0; k < NCH; ++k)
        lsum += __logf(Ov[k].x) + __logf(Ov[k].y) + __logf(Ov[k].z) + __logf(Ov[k].w);

    // Cross-wave / cross-chunk exclusive prefixes via 16-value LDS scan.
    // Row position = (k*BDIM + tid)*4 + j  ->  scan order k-major: index = k*4 + wave.
    __shared__ float wtot[NCH * 4], wpre[NCH * 4];
    __shared__ float s_total;
    if (lane == 63) {
        #pragma unroll
        for (int k = 0; k < NCH; ++k) wtot[k * 4 + wave] = sc[k];
    }
    __syncthreads();
    if (tid == 0) {
        float a = 0.f;
        #pragma unroll
        for (int i = 0; i < NCH * 4; ++i) { wpre[i] = a; a += wtot[i]; }
        s_total = a;
    }
    __syncthreads();
    const float total = s_total;

    // qsum = sum exp(2*tp / (TAU*(rank+total))), fast rcp for the divide.
    const float c = 2.0f / 0.95f;
    float qsum = 0.f;
    #pragma unroll
    for (int k = 0; k < NCH; ++k) {
        const float excl = wpre[k * 4 + wave] + (sc[k] - s[k]);
        const float rbase = (float)(4 * (k * BDIM + tid) + 1) + total;
        #pragma unroll
        for (int j = 0; j < 4; ++j) {
            float tp = excl + p[k][j];
            qsum += __expf(c * tp * __builtin_amdgcn_rcpf(rbase + (float)j));
        }
    }

    // Block reduction of (qsum, lsum).
    #pragma unroll
    for (int d = 32; d > 0; d >>= 1) {
        qsum += __shfl_down(qsum, d, 64);
        lsum += __shfl_down(lsum, d, 64);
    }
    __shared__ float sq[4], sl[4];
    if (lane == 0) { sq[wave] = qsum; sl[wave] = lsum; }
    __syncthreads();
    if (tid == 0) {
        float Q = 0.f, L = 0.f;
        #pragma unroll
        for (int w = 0; w < 4; ++w) { Q += sq[w]; L += sl[w]; }
        row_out[b] = L / Q;
    }
}

__global__ __launch_bounds__(256) void attncut_final_kernel(
    const float* __restrict__ row_out, float* __restrict__ d_out)
{
    const int tid = threadIdx.x;            // 0..255
    const int lane = tid & 63, wave = tid >> 6;
    const float4* r4 = reinterpret_cast<const float4*>(row_out);
    float s = 0.f;
    #pragma unroll
    for (int k = 0; k < 4; ++k) {
        float4 v = r4[tid + k * 256];
        s += v.x + v.y + v.z + v.w;
    }
    #pragma unroll
    for (int d = 32; d > 0; d >>= 1) s += __shfl_down(s, d, 64);
    __shared__ float sm[4];
    if (lane == 0) sm[wave] = s;
    __syncthreads();
    if (tid == 0) {
        float t = sm[0] + sm[1] + sm[2] + sm[3];
        d_out[0] = -t / (float)NROWS;
    }
}

extern "C" void kernel_launch(void* const* d_in, const int* in_sizes, int n_in,
                              void* d_out, int out_size, void* d_ws, size_t ws_size,
                              hipStream_t stream) {
    const float* output = (const float*)d_in[0];   // [B,S,1] fp32
    const float* labels = (const float*)d_in[1];   // [B,S]   fp32
    float* out  = (float*)d_out;
    float* rows = (float*)d_ws;                    // NROWS floats of scratch

    attncut_row_kernel<<<NROWS, BDIM, 0, stream>>>(output, labels, rows);
    attncut_final_kernel<<<1, 256, 0, stream>>>(rows, out);
}